// Round 3
// baseline (587.041 us; speedup 1.0000x reference)
//
#include <hip/hip_runtime.h>
#include <math.h>

#define PI_F 3.14159265358979323846f

typedef _Float16 h8 __attribute__((ext_vector_type(8)));
typedef float f4 __attribute__((ext_vector_type(4)));

__device__ __forceinline__ float sigm_(float x){ return 1.0f/(1.0f+__expf(-x)); }
__device__ __forceinline__ float silu_(float x){ return x*sigm_(x); }
__device__ __forceinline__ h8 ldh8(const _Float16* p){
    return __builtin_bit_cast(h8, *(const float4*)(p));
}

// B layout (fp16, in d_ws):
//   B1T: per layer [n<112][k<192]  (n<50: Ws col, 50..99: Wg col, 100+: 0)
//   B2T: per layer [n<64][k<192]   (n<50: Wv col, else 0)
//   k segments: [0,50): W_hi(c=k) | [64,114): W_hi(c=k-64) | [128,178): W_lo(c=k-128)
#define B1_PER_L 21504
#define B2_PER_L 12288
#define B1_TOT   129024
#define B_TOT    202752

// A: 104 rows x 128 halves (26624 B -> 6 blocks/CU). Row stride is bank-aligned,
// so columns are XOR-swizzled in 16B (8-half) units: col ^= (row&7)<<3.
// H rows 0..23; Q rows 24..95; reads of rows 96..103 (tile over-reach) hit
// garbage whose C rows are never stored.
#define AROWS 104

// ---------------------------------------------------------------------------
// K1 (merged): block 0 = pre[] + output boundary zeros; blocks [1..nTb] =
// spine table (4 entries/block, 1/wave); blocks (nTb..] = fill_B.
// T layout: per entry e, 50 float2 pairs {col kl, col 50+kl}.
// ---------------------------------------------------------------------------
__global__ void precompute_all(const float* __restrict__ W_embed,
                               const float* __restrict__ Wr1,
                               const float* __restrict__ br1,
                               const float* __restrict__ Wr2,
                               const float* __restrict__ Ws,
                               const float* __restrict__ Wg,
                               const float* __restrict__ Wv,
                               float* __restrict__ pre,
                               float* __restrict__ T,
                               int tabN,
                               _Float16* __restrict__ B,
                               float* __restrict__ out,
                               int nTb)
{
    const int bid = blockIdx.x;
    const int tid = threadIdx.x;
    const float wdt = 0.06f / 9.0f;

    if (bid == 0) {
        // ---- zero output boundary rows (t=0, t=513) : 64 batches x 6 floats
        for (int i = tid; i < 384; i += 256) {
            int b = i / 6, r = i - b * 6;
            int t = (r < 3) ? 0 : 513;
            out[((size_t)(b * 514 + t)) * 3 + (r % 3)] = 0.0f;
        }
        // ---- pre[]: s1 trajectory + bar-edge weights
        __shared__ float s1[50];
        __shared__ float hid[64];
        if (tid < 50) s1[tid] = W_embed[tid] + W_embed[50 + tid];
        __syncthreads();

        const float rbar = 0.05f;
        const float fcb = 0.5f * (__cosf(PI_F * (rbar / 0.06f)) + 1.0f);
        float emb[12];
#pragma unroll
        for (int i = 0; i < 10; ++i) {
            float d = (rbar - (float)i * wdt) / wdt;
            emb[i] = __expf(-d * d) * fcb;
        }
        emb[10] = 0.0f; emb[11] = 1.0f;

        for (int l = 0; l < 6; ++l) {
            if (tid < 50) pre[l * 50 + tid] = s1[tid];
            if (tid < 64) {
                float a = br1[l * 64 + tid];
#pragma unroll
                for (int i = 0; i < 12; ++i) a += emb[i] * Wr1[l * 768 + i * 64 + tid];
                hid[tid] = silu_(a);
            }
            __syncthreads();
            for (int m = tid; m < 250; m += 256) {
                float acc = 0.0f;
                for (int j = 0; j < 64; ++j) acc += hid[j] * Wr2[l * 16000 + j * 250 + m];
                pre[300 + l * 250 + m] = acc * fcb;
            }
            float sacc = 0.0f;
            if (tid < 50) {
                for (int c = 0; c < 50; ++c) sacc += s1[c] * Ws[l * 2500 + c * 50 + tid];
            }
            __syncthreads();
            if (tid < 50) s1[tid] = silu_(sacc);
            __syncthreads();
        }
    } else if (bid <= nTb) {
        // ---- spine-edge table entry per wave ----
        const int e = (bid - 1) * 4 + (tid >> 6);
        const int lane = tid & 63;
        const int total = 6 * (tabN + 1);
        if (e >= total) return;
        const int l = e / (tabN + 1);
        const int i = e - l * (tabN + 1);

        float r = (float)i * (0.06f / (float)tabN);
        float t = fminf(r * (1.0f / 0.06f), 1.0f);
        float fc = 0.5f * (__cosf(PI_F * t) + 1.0f);
        float emb[10];
#pragma unroll
        for (int k = 0; k < 10; ++k) {
            float d = (r - (float)k * wdt) / wdt;
            emb[k] = __expf(-d * d) * fc;
        }
        float a = br1[l * 64 + lane] + Wr1[l * 768 + 640 + lane];  // edge_attr [1,0]
#pragma unroll
        for (int k = 0; k < 10; ++k) a += emb[k] * Wr1[l * 768 + k * 64 + lane];
        float hv = silu_(a);

        float acc0 = 0.0f, acc1 = 0.0f;
        const float* wr2 = Wr2 + l * 16000;
        for (int j = 0; j < 64; ++j) {
            float hj = __shfl(hv, j);
            acc0 += hj * wr2[j * 250 + lane];
            acc1 += hj * wr2[j * 250 + 64 + lane];
        }
        // pair layout: T[e][2*c]   = col c      (acc0 @ lane c)
        //              T[e][2*c+1] = col 50+c   (c<14: acc0 @ lane 50+c, else acc1 @ lane c-14)
        float* tp = T + (size_t)e * 100;
        float sh0 = __shfl(acc0, lane + 50);   // wraps mod 64; selected only for lane<14
        float sh1 = __shfl(acc1, lane - 14);
        float vb = ((lane < 14) ? sh0 : sh1) * fc;
        if (lane < 50) *(float2*)(tp + 2 * lane) = make_float2(acc0 * fc, vb);
    } else {
        // ---- fill_B ----
        int idx = (bid - 1 - nTb) * 256 + tid;
        if (idx >= B_TOT) return;
        int l, n, k, which;
        size_t off;
        if (idx < B1_TOT) {
            l = idx / B1_PER_L; int r = idx - l * B1_PER_L;
            n = r / 192; k = r - n * 192; which = 0;
            off = (size_t)l * B1_PER_L + n * 192 + k;
        } else {
            int j = idx - B1_TOT;
            l = j / B2_PER_L; int r = j - l * B2_PER_L;
            n = r / 192; k = r - n * 192; which = 1;
            off = B1_TOT + (size_t)l * B2_PER_L + n * 192 + k;
        }
        int seg = -1, c = 0;
        if (k < 50)                  { seg = 0; c = k; }
        else if (k >= 64 && k < 114) { seg = 1; c = k - 64; }
        else if (k >= 128 && k < 178){ seg = 2; c = k - 128; }
        _Float16 val = (_Float16)0.0f;
        if (seg >= 0) {
            float w = 0.0f;
            if (which == 0) {
                if (n < 50)       w = Ws[l * 2500 + c * 50 + n];
                else if (n < 100) w = Wg[l * 2500 + c * 50 + (n - 50)];
            } else {
                if (n < 50)       w = Wv[l * 2500 + c * 50 + n];
            }
            _Float16 hi = (_Float16)w;
            val = (seg < 2) ? hi : (_Float16)(w - (float)hi);
        }
        B[off] = val;
    }
}

// ---------------------------------------------------------------------------
// K2: fused forward. Block = 8 windows (2/wave). A = 104x128 halves with XOR
// swizzle (26624 B LDS -> 6 blocks/CU @ launch_bounds(256,6)). C stored
// TRANSPOSED (outHT[24][100], outQT[72][50]) in overlay; discarded C rows
// (from garbage A rows) are not stored. No register pipelining: stay inside
// the 64-VGPR envelope (allocator spills anything beyond it — r1/r2 evidence).
// ---------------------------------------------------------------------------
__global__ __launch_bounds__(256, 6)
void fused_main(const float* __restrict__ y,
                const float* __restrict__ W_embed,
                const float* __restrict__ W_out,
                const float* __restrict__ pre,
                const float* __restrict__ T,
                int tabN,
                const _Float16* __restrict__ Bws,
                float* __restrict__ out)
{
    __shared__ __align__(16) char LB[AROWS * 128 * 2];   // 26624 B
    _Float16* A   = (_Float16*)LB;
    float* outHT  = (float*)LB;          // [24][100]
    float* outQT  = (float*)LB + 2400;   // [72][50]

    const int tid  = threadIdx.x;
    const int wave = tid >> 6;
    const int lane = tid & 63;
    const int kl   = (lane < 50) ? lane : 49;
    const int fm   = lane & 15;
    const int fq   = lane >> 4;

    const _Float16* B1 = Bws;
    const _Float16* B2 = Bws + B1_TOT;

    // swizzled A fragment read: 4 k-frags of row `row` for this lane
    auto lda = [&](int row, h8& a0, h8& a1, h8& a2, h8& a3) {
        const int base = row * 128 + ((fq ^ (row & 3)) << 3);
        const int x32  = ((row >> 2) & 1) << 5;
        a0 = ldh8(A + base + x32);
        a1 = ldh8(A + base + (32 - x32));
        a2 = ldh8(A + base + 64 + x32);
        a3 = ldh8(A + base + 96 - x32);
    };

    // ---- per-window geometry ----
    float offx[2], offy[2], u3x_[2], u3y_[2], uspx_[2], uspy_[2], fr_[2];
    int   ti_[2], inr_[2];
#pragma unroll
    for (int w = 0; w < 2; ++w) {
        int wid = blockIdx.x * 8 + wave * 2 + w;
        int b = wid >> 9, tw = wid & 511;
        const float* yb = y + ((size_t)(b * 514 + tw)) * 6;
        float c0x = yb[0], c0y = yb[1];
        float c1x = yb[6], c1y = yb[7], a1 = yb[8];
        float sn, cs; __sincosf(a1, &sn, &cs);
        offx[w] = -0.05f * sn; offy[w] = 0.05f * cs;
        float svx = c0x - c1x, svy = c0y - c1y;
        float r_sp = sqrtf(svx * svx + svy * svy);
        float inv_sp = 1.0f / (r_sp + 1e-12f);
        uspx_[w] = svx * inv_sp; uspy_[w] = svy * inv_sp;
        float rb2 = sqrtf(offx[w] * offx[w] + offy[w] * offy[w]);
        float invb = 1.0f / (rb2 + 1e-12f);
        u3x_[w] = -offx[w] * invb; u3y_[w] = -offy[w] * invb;
        float tp = r_sp * ((float)tabN / 0.06f);
        inr_[w] = tp < (float)tabN;
        int ti = (int)tp;
        if (ti > tabN - 1) ti = tabN - 1;
        if (ti < 0) ti = 0;
        ti_[w] = ti; fr_[w] = tp - (float)ti;
    }

    // ---- initial states ----
    float s3[2], s4[2], s5[2];
    float v3x[2], v3y[2], v3z[2], v4x[2], v4y[2], v4z[2], v5x[2], v5y[2], v5z[2];
    {
        float i35 = W_embed[kl] + W_embed[100 + kl];
        float i4  = W_embed[kl] + W_embed[50 + kl];
#pragma unroll
        for (int w = 0; w < 2; ++w) {
            s3[w] = i35; s5[w] = i35; s4[w] = i4;
            v3x[w] = v3y[w] = v3z[w] = 0.0f;
            v4x[w] = v4y[w] = v4z[w] = 0.0f;
            v5x[w] = v5y[w] = v5z[w] = 0.0f;
        }
    }

    for (int l = 0; l < 6; ++l) {
        __syncthreads();   // overlay region free

        // ---- per-layer T (L2-resident, pair layout) + pre loads ----
        float s1l = pre[l * 50 + kl];
        const float* wbp = pre + 300 + l * 250;
        float wb0 = wbp[kl], wb1 = wbp[50 + kl], wb2 = wbp[100 + kl],
              wb3 = wbp[150 + kl], wb4 = wbp[200 + kl];

        const float THIRD = 1.0f / 3.0f;
#pragma unroll
        for (int w = 0; w < 2; ++w) {
            const float* tb = T + ((size_t)(l * (tabN + 1) + ti_[w])) * 100 + 2 * kl;
            float2 t0 = *(const float2*)tb;
            float2 t1 = *(const float2*)(tb + 100);
            float wsp0 = inr_[w] ? (t0.x + fr_[w] * (t1.x - t0.x)) : 0.0f;
            float wsp1 = inr_[w] ? (t0.y + fr_[w] * (t1.y - t0.y)) : 0.0f;

            float u3x = u3x_[w], u3y = u3y_[w];
            float dot3 = v4x[w] * u3x + v4y[w] * u3y;
            float ms3 = wb0 * s4[w] + wb2 * dot3;
            float ms5 = wb0 * s4[w] - wb2 * dot3;
            float ms4 = wsp0 * s1l;
            float bAx = wb1 * s4[w] * u3x - wb3 * v4z[w] * u3y;
            float bAy = wb1 * s4[w] * u3y + wb3 * v4z[w] * u3x;
            float bBx = wb4 * (dot3 * u3x - v4x[w] * THIRD);
            float bBy = wb4 * (dot3 * u3y - v4y[w] * THIRD);
            float crz = wb3 * (v4x[w] * u3y - v4y[w] * u3x);
            float mzc = -wb4 * v4z[w] * THIRD;

            float vals[12];
            vals[0] = s3[w] + ms3;
            vals[1] = s4[w] + ms4;
            vals[2] = s5[w] + ms5;
            vals[3] = v3x[w] + bAx + bBx;
            vals[4] = v3y[w] + bAy + bBy;
            vals[5] = v3z[w] + crz + mzc;
            vals[6] = v4x[w] + wsp1 * s1l * uspx_[w];
            vals[7] = v4y[w] + wsp1 * s1l * uspy_[w];
            vals[8] = v4z[w];
            vals[9]  = v5x[w] - bAx + bBx;
            vals[10] = v5y[w] - bAy + bBy;
            vals[11] = v5z[w] - crz + mzc;

            int wv = wave * 2 + w;
#pragma unroll
            for (int q = 0; q < 12; ++q) {
                int row = (q < 3) ? (wv * 3 + q) : (24 + wv * 9 + (q - 3));
                float x = (lane < 50) ? vals[q] : 0.0f;
                _Float16 hi = (_Float16)x;
                _Float16 lo = (_Float16)(x - (float)hi);
                int col = lane ^ ((row & 7) << 3);
                A[row * 128 + col]      = hi;
                A[row * 128 + col + 64] = lo;
            }
        }
        __syncthreads();   // A complete (no pad rows needed: garbage C rows unstored)

        // ---- MFMA phase (B loads inside each sub-block: short live ranges) ----
        f4 cst[9];
        const _Float16* B1l = B1 + (size_t)l * B1_PER_L;
        const _Float16* B2l = B2 + (size_t)l * B2_PER_L;

        // ji0: H, n-tile = wave (n = wave*16+fm <= 63)
        {
            const _Float16* bp = B1l + (wave * 16 + fm) * 192 + fq * 8;
            h8 b0 = ldh8(bp), b1 = ldh8(bp + 32), b2 = ldh8(bp + 64),
               b3 = ldh8(bp + 96), b4 = ldh8(bp + 128), b5 = ldh8(bp + 160);
#pragma unroll
            for (int mt = 0; mt < 2; ++mt) {
                h8 a0, a1, a2, a3;
                lda(mt * 16 + fm, a0, a1, a2, a3);
                f4 acc = {0.0f, 0.0f, 0.0f, 0.0f};
                acc = __builtin_amdgcn_mfma_f32_16x16x32_f16(a0, b0, acc, 0, 0, 0);
                acc = __builtin_amdgcn_mfma_f32_16x16x32_f16(a1, b1, acc, 0, 0, 0);
                acc = __builtin_amdgcn_mfma_f32_16x16x32_f16(a2, b2, acc, 0, 0, 0);
                acc = __builtin_amdgcn_mfma_f32_16x16x32_f16(a3, b3, acc, 0, 0, 0);
                acc = __builtin_amdgcn_mfma_f32_16x16x32_f16(a0, b4, acc, 0, 0, 0);
                acc = __builtin_amdgcn_mfma_f32_16x16x32_f16(a1, b5, acc, 0, 0, 0);
                cst[mt] = acc;
            }
        }
        // ji1: H, n-tile = 4+wave (waves 0..2)
        if (wave < 3) {
            const _Float16* bp = B1l + ((4 + wave) * 16 + fm) * 192 + fq * 8;
            h8 b0 = ldh8(bp), b1 = ldh8(bp + 32), b2 = ldh8(bp + 64),
               b3 = ldh8(bp + 96), b4 = ldh8(bp + 128), b5 = ldh8(bp + 160);
#pragma unroll
            for (int mt = 0; mt < 2; ++mt) {
                h8 a0, a1, a2, a3;
                lda(mt * 16 + fm, a0, a1, a2, a3);
                f4 acc = {0.0f, 0.0f, 0.0f, 0.0f};
                acc = __builtin_amdgcn_mfma_f32_16x16x32_f16(a0, b0, acc, 0, 0, 0);
                acc = __builtin_amdgcn_mfma_f32_16x16x32_f16(a1, b1, acc, 0, 0, 0);
                acc = __builtin_amdgcn_mfma_f32_16x16x32_f16(a2, b2, acc, 0, 0, 0);
                acc = __builtin_amdgcn_mfma_f32_16x16x32_f16(a3, b3, acc, 0, 0, 0);
                acc = __builtin_amdgcn_mfma_f32_16x16x32_f16(a0, b4, acc, 0, 0, 0);
                acc = __builtin_amdgcn_mfma_f32_16x16x32_f16(a1, b5, acc, 0, 0, 0);
                cst[2 + mt] = acc;
            }
        }
        // ji2: Q, n-tile = wave; Q A-rows start at 24
        {
            const _Float16* bp = B2l + (wave * 16 + fm) * 192 + fq * 8;
            h8 b0 = ldh8(bp), b1 = ldh8(bp + 32), b2 = ldh8(bp + 64),
               b3 = ldh8(bp + 96), b4 = ldh8(bp + 128), b5 = ldh8(bp + 160);
#pragma unroll
            for (int mt = 0; mt < 5; ++mt) {
                h8 a0, a1, a2, a3;
                lda(24 + mt * 16 + fm, a0, a1, a2, a3);
                f4 acc = {0.0f, 0.0f, 0.0f, 0.0f};
                acc = __builtin_amdgcn_mfma_f32_16x16x32_f16(a0, b0, acc, 0, 0, 0);
                acc = __builtin_amdgcn_mfma_f32_16x16x32_f16(a1, b1, acc, 0, 0, 0);
                acc = __builtin_amdgcn_mfma_f32_16x16x32_f16(a2, b2, acc, 0, 0, 0);
                acc = __builtin_amdgcn_mfma_f32_16x16x32_f16(a3, b3, acc, 0, 0, 0);
                acc = __builtin_amdgcn_mfma_f32_16x16x32_f16(a0, b4, acc, 0, 0, 0);
                acc = __builtin_amdgcn_mfma_f32_16x16x32_f16(a1, b5, acc, 0, 0, 0);
                cst[4 + mt] = acc;
            }
        }
        __syncthreads();   // all A-reads done -> overlay safe

        // ---- C writes, transposed; skip discarded rows (>=24 H, >=72 Q) ----
        {
            int n0 = wave * 16 + fm;                     // < 64
#pragma unroll
            for (int mt = 0; mt < 2; ++mt)
#pragma unroll
                for (int i = 0; i < 4; ++i) {
                    int r = mt * 16 + fq * 4 + i;
                    if (r < 24) outHT[r * 100 + n0] = cst[mt][i];
                }
            if (wave < 3) {
                int n1 = (4 + wave) * 16 + fm;           // 64..111
                if (n1 < 100) {
#pragma unroll
                    for (int mt = 0; mt < 2; ++mt)
#pragma unroll
                        for (int i = 0; i < 4; ++i) {
                            int r = mt * 16 + fq * 4 + i;
                            if (r < 24) outHT[r * 100 + n1] = cst[2 + mt][i];
                        }
                }
            }
            if (n0 < 50) {
#pragma unroll
                for (int mt = 0; mt < 5; ++mt)
#pragma unroll
                    for (int i = 0; i < 4; ++i) {
                        int r = mt * 16 + fq * 4 + i;
                        if (r < 72) outQT[r * 50 + n0] = cst[4 + mt][i];
                    }
            }
        }
        __syncthreads();   // outputs ready

        // ---- readback + activations (stride-1 in kl: conflict-free) ----
#pragma unroll
        for (int w = 0; w < 2; ++w) {
            int wv = wave * 2 + w;
            int mb = wv * 3, qb = wv * 9;
            float as3 = outHT[(mb    ) * 100 + kl];
            float as4 = outHT[(mb + 1) * 100 + kl];
            float as5 = outHT[(mb + 2) * 100 + kl];
            float ag3 = outHT[(mb    ) * 100 + 50 + kl];
            float ag4 = outHT[(mb + 1) * 100 + 50 + kl];
            float ag5 = outHT[(mb + 2) * 100 + 50 + kl];
            float g3 = sigm_(ag3), g4 = sigm_(ag4), g5 = sigm_(ag5);
            s3[w] = silu_(as3); s4[w] = silu_(as4); s5[w] = silu_(as5);
            v3x[w] = outQT[(qb    ) * 50 + kl] * g3;
            v3y[w] = outQT[(qb + 1) * 50 + kl] * g3;
            v3z[w] = outQT[(qb + 2) * 50 + kl] * g3;
            v4x[w] = outQT[(qb + 3) * 50 + kl] * g4;
            v4y[w] = outQT[(qb + 4) * 50 + kl] * g4;
            v4z[w] = outQT[(qb + 5) * 50 + kl] * g4;
            v5x[w] = outQT[(qb + 6) * 50 + kl] * g5;
            v5y[w] = outQT[(qb + 7) * 50 + kl] * g5;
            v5z[w] = outQT[(qb + 8) * 50 + kl] * g5;
        }
    }

    // ---- output epilogue ----
    float wo = (lane < 50) ? W_out[lane] : 0.0f;
#pragma unroll
    for (int w = 0; w < 2; ++w) {
        float px  = (v3x[w] + v4x[w] + v5x[w]) * wo;
        float py  = (v3y[w] + v4y[w] + v5y[w]) * wo;
        float dxv = (v3x[w] - v5x[w]) * wo;
        float dyv = (v3y[w] - v5y[w]) * wo;
#pragma unroll
        for (int o = 32; o > 0; o >>= 1) {
            px  += __shfl_xor(px, o);
            py  += __shfl_xor(py, o);
            dxv += __shfl_xor(dxv, o);
            dyv += __shfl_xor(dyv, o);
        }
        if (lane == 0) {
            int wid = blockIdx.x * 8 + wave * 2 + w;
            int b = wid >> 9, tw = wid & 511;
            float* op = out + ((size_t)(b * 514 + (tw + 1))) * 3;
            op[0] = px;
            op[1] = py;
            op[2] = offx[w] * dyv - offy[w] * dxv;
        }
    }
}

// ---------------------------------------------------------------------------
extern "C" void kernel_launch(void* const* d_in, const int* in_sizes, int n_in,
                              void* d_out, int out_size, void* d_ws, size_t ws_size,
                              hipStream_t stream) {
    const float* y       = (const float*)d_in[0];
    const float* W_embed = (const float*)d_in[1];
    const float* Wr1     = (const float*)d_in[2];
    const float* br1     = (const float*)d_in[3];
    const float* Wr2     = (const float*)d_in[4];
    const float* Ws      = (const float*)d_in[5];
    const float* Wv      = (const float*)d_in[6];
    const float* Wg      = (const float*)d_in[7];
    const float* W_out   = (const float*)d_in[8];
    float* out = (float*)d_out;

    _Float16* Bws = (_Float16*)d_ws;                         // 405504 B
    float* pre = (float*)((char*)d_ws + B_TOT * 2);          // 1800 floats
    float* T   = pre + 1800;

    // tabN=1024: table = 2.46 MB -> per-XCD-L2-resident; absmax verified
    // unchanged vs tabN=2048 (precision is fp16-split-dominated).
    int tabN = 1024;
    while (tabN > 64 &&
           (size_t)B_TOT * 2 + (size_t)(1800 + 6 * (tabN + 1) * 100) * sizeof(float) > ws_size)
        tabN >>= 1;

    int nTb = (6 * (tabN + 1) + 3) / 4;
    int nFb = (B_TOT + 255) / 256;
    precompute_all<<<1 + nTb + nFb, 256, 0, stream>>>(
        W_embed, Wr1, br1, Wr2, Ws, Wg, Wv, pre, T, tabN, Bws, out, nTb);
    fused_main<<<4096, 256, 0, stream>>>(y, W_embed, W_out, pre, T, tabN, Bws, out);
}

// Round 4
// 376.648 us; speedup vs baseline: 1.5586x; 1.5586x over previous
//
#include <hip/hip_runtime.h>
#include <math.h>

#define PI_F 3.14159265358979323846f

typedef _Float16 h8 __attribute__((ext_vector_type(8)));
typedef float f4 __attribute__((ext_vector_type(4)));

__device__ __forceinline__ float sigm_(float x){ return 1.0f/(1.0f+__expf(-x)); }
__device__ __forceinline__ float silu_(float x){ return x*sigm_(x); }
__device__ __forceinline__ h8 ldh8(const _Float16* p){
    return __builtin_bit_cast(h8, *(const float4*)(p));
}

// B layout (fp16, in d_ws):
//   B1T: per layer [n<112][k<192]  (n<50: Ws col, 50..99: Wg col, 100+: 0)
//   B2T: per layer [n<64][k<192]   (n<50: Wv col, else 0)
//   k segments: [0,50): W_hi(c=k) | [64,114): W_hi(c=k-64) | [128,178): W_lo(c=k-128)
#define B1_PER_L 21504
#define B2_PER_L 12288
#define B1_TOT   129024
#define B_TOT    202752

// A: 104 rows x 128 halves (26624 B; 6 blocks/CU = 159744 B <= 160 KiB).
// Row stride is bank-aligned, so columns are XOR-swizzled in 16B (8-half)
// units: col ^= (row&7)<<3. H rows 0..23; Q rows 24..95; reads of rows
// 96..103 (tile over-reach) hit garbage whose C rows are never stored.
// Verified correct in r3 (absmax unchanged).
#define AROWS 104

// ---------------------------------------------------------------------------
// K1 (merged): block 0 = pre[] + output boundary zeros; blocks [1..nTb] =
// spine table (4 entries/block, 1/wave); blocks (nTb..] = fill_B.
// T layout: per entry e, 50 float2 pairs {col kl, col 50+kl}.
// ---------------------------------------------------------------------------
__global__ void precompute_all(const float* __restrict__ W_embed,
                               const float* __restrict__ Wr1,
                               const float* __restrict__ br1,
                               const float* __restrict__ Wr2,
                               const float* __restrict__ Ws,
                               const float* __restrict__ Wg,
                               const float* __restrict__ Wv,
                               float* __restrict__ pre,
                               float* __restrict__ T,
                               int tabN,
                               _Float16* __restrict__ B,
                               float* __restrict__ out,
                               int nTb)
{
    const int bid = blockIdx.x;
    const int tid = threadIdx.x;
    const float wdt = 0.06f / 9.0f;

    if (bid == 0) {
        // ---- zero output boundary rows (t=0, t=513) : 64 batches x 6 floats
        for (int i = tid; i < 384; i += 256) {
            int b = i / 6, r = i - b * 6;
            int t = (r < 3) ? 0 : 513;
            out[((size_t)(b * 514 + t)) * 3 + (r % 3)] = 0.0f;
        }
        // ---- pre[]: s1 trajectory + bar-edge weights
        __shared__ float s1[50];
        __shared__ float hid[64];
        if (tid < 50) s1[tid] = W_embed[tid] + W_embed[50 + tid];
        __syncthreads();

        const float rbar = 0.05f;
        const float fcb = 0.5f * (__cosf(PI_F * (rbar / 0.06f)) + 1.0f);
        float emb[12];
#pragma unroll
        for (int i = 0; i < 10; ++i) {
            float d = (rbar - (float)i * wdt) / wdt;
            emb[i] = __expf(-d * d) * fcb;
        }
        emb[10] = 0.0f; emb[11] = 1.0f;

        for (int l = 0; l < 6; ++l) {
            if (tid < 50) pre[l * 50 + tid] = s1[tid];
            if (tid < 64) {
                float a = br1[l * 64 + tid];
#pragma unroll
                for (int i = 0; i < 12; ++i) a += emb[i] * Wr1[l * 768 + i * 64 + tid];
                hid[tid] = silu_(a);
            }
            __syncthreads();
            for (int m = tid; m < 250; m += 256) {
                float acc = 0.0f;
                for (int j = 0; j < 64; ++j) acc += hid[j] * Wr2[l * 16000 + j * 250 + m];
                pre[300 + l * 250 + m] = acc * fcb;
            }
            float sacc = 0.0f;
            if (tid < 50) {
                for (int c = 0; c < 50; ++c) sacc += s1[c] * Ws[l * 2500 + c * 50 + tid];
            }
            __syncthreads();
            if (tid < 50) s1[tid] = silu_(sacc);
            __syncthreads();
        }
    } else if (bid <= nTb) {
        // ---- spine-edge table entry per wave ----
        const int e = (bid - 1) * 4 + (tid >> 6);
        const int lane = tid & 63;
        const int total = 6 * (tabN + 1);
        if (e >= total) return;
        const int l = e / (tabN + 1);
        const int i = e - l * (tabN + 1);

        float r = (float)i * (0.06f / (float)tabN);
        float t = fminf(r * (1.0f / 0.06f), 1.0f);
        float fc = 0.5f * (__cosf(PI_F * t) + 1.0f);
        float emb[10];
#pragma unroll
        for (int k = 0; k < 10; ++k) {
            float d = (r - (float)k * wdt) / wdt;
            emb[k] = __expf(-d * d) * fc;
        }
        float a = br1[l * 64 + lane] + Wr1[l * 768 + 640 + lane];  // edge_attr [1,0]
#pragma unroll
        for (int k = 0; k < 10; ++k) a += emb[k] * Wr1[l * 768 + k * 64 + lane];
        float hv = silu_(a);

        float acc0 = 0.0f, acc1 = 0.0f;
        const float* wr2 = Wr2 + l * 16000;
        for (int j = 0; j < 64; ++j) {
            float hj = __shfl(hv, j);
            acc0 += hj * wr2[j * 250 + lane];
            acc1 += hj * wr2[j * 250 + 64 + lane];
        }
        // pair layout: T[e][2*c]   = col c      (acc0 @ lane c)
        //              T[e][2*c+1] = col 50+c   (c<14: acc0 @ lane 50+c, else acc1 @ lane c-14)
        float* tp = T + (size_t)e * 100;
        float sh0 = __shfl(acc0, lane + 50);   // wraps mod 64; selected only for lane<14
        float sh1 = __shfl(acc1, lane - 14);
        float vb = ((lane < 14) ? sh0 : sh1) * fc;
        if (lane < 50) *(float2*)(tp + 2 * lane) = make_float2(acc0 * fc, vb);
    } else {
        // ---- fill_B ----
        int idx = (bid - 1 - nTb) * 256 + tid;
        if (idx >= B_TOT) return;
        int l, n, k, which;
        size_t off;
        if (idx < B1_TOT) {
            l = idx / B1_PER_L; int r = idx - l * B1_PER_L;
            n = r / 192; k = r - n * 192; which = 0;
            off = (size_t)l * B1_PER_L + n * 192 + k;
        } else {
            int j = idx - B1_TOT;
            l = j / B2_PER_L; int r = j - l * B2_PER_L;
            n = r / 192; k = r - n * 192; which = 1;
            off = B1_TOT + (size_t)l * B2_PER_L + n * 192 + k;
        }
        int seg = -1, c = 0;
        if (k < 50)                  { seg = 0; c = k; }
        else if (k >= 64 && k < 114) { seg = 1; c = k - 64; }
        else if (k >= 128 && k < 178){ seg = 2; c = k - 128; }
        _Float16 val = (_Float16)0.0f;
        if (seg >= 0) {
            float w = 0.0f;
            if (which == 0) {
                if (n < 50)       w = Ws[l * 2500 + c * 50 + n];
                else if (n < 100) w = Wg[l * 2500 + c * 50 + (n - 50)];
            } else {
                if (n < 50)       w = Wv[l * 2500 + c * 50 + n];
            }
            _Float16 hi = (_Float16)w;
            val = (seg < 2) ? hi : (_Float16)(w - (float)hi);
        }
        B[off] = val;
    }
}

// ---------------------------------------------------------------------------
// K2: fused forward. Block = 8 windows (2/wave). A = 104x128 halves with XOR
// swizzle, 26624 B LDS. launch_bounds STAYS (256,4): the 2nd arg is only an
// allocator floor — forcing 5/6 made the allocator spill cst[] (r1: 1 GB,
// r3: 418 MB scratch traffic). With the natural 64-VGPR allocation, hardware
// still reaches 6 blocks/CU off the LDS footprint (6*26624 = 159744 <= 160K).
// C stored TRANSPOSED (outHT[24][100], outQT[72][50]); garbage C rows from
// A-tile over-reach are simply not stored.
// ---------------------------------------------------------------------------
__global__ __launch_bounds__(256, 4)
void fused_main(const float* __restrict__ y,
                const float* __restrict__ W_embed,
                const float* __restrict__ W_out,
                const float* __restrict__ pre,
                const float* __restrict__ T,
                int tabN,
                const _Float16* __restrict__ Bws,
                float* __restrict__ out)
{
    __shared__ __align__(16) char LB[AROWS * 128 * 2];   // 26624 B
    _Float16* A   = (_Float16*)LB;
    float* outHT  = (float*)LB;          // [24][100]
    float* outQT  = (float*)LB + 2400;   // [72][50]

    const int tid  = threadIdx.x;
    const int wave = tid >> 6;
    const int lane = tid & 63;
    const int kl   = (lane < 50) ? lane : 49;
    const int fm   = lane & 15;
    const int fq   = lane >> 4;

    const _Float16* B1 = Bws;
    const _Float16* B2 = Bws + B1_TOT;

    // swizzled A fragment read: 4 k-frags of row `row` for this lane
    auto lda = [&](int row, h8& a0, h8& a1, h8& a2, h8& a3) {
        const int base = row * 128 + ((fq ^ (row & 3)) << 3);
        const int x32  = ((row >> 2) & 1) << 5;
        a0 = ldh8(A + base + x32);
        a1 = ldh8(A + base + (32 - x32));
        a2 = ldh8(A + base + 64 + x32);
        a3 = ldh8(A + base + 96 - x32);
    };

    // ---- per-window geometry ----
    float offx[2], offy[2], u3x_[2], u3y_[2], uspx_[2], uspy_[2], fr_[2];
    int   ti_[2], inr_[2];
#pragma unroll
    for (int w = 0; w < 2; ++w) {
        int wid = blockIdx.x * 8 + wave * 2 + w;
        int b = wid >> 9, tw = wid & 511;
        const float* yb = y + ((size_t)(b * 514 + tw)) * 6;
        float c0x = yb[0], c0y = yb[1];
        float c1x = yb[6], c1y = yb[7], a1 = yb[8];
        float sn, cs; __sincosf(a1, &sn, &cs);
        offx[w] = -0.05f * sn; offy[w] = 0.05f * cs;
        float svx = c0x - c1x, svy = c0y - c1y;
        float r_sp = sqrtf(svx * svx + svy * svy);
        float inv_sp = 1.0f / (r_sp + 1e-12f);
        uspx_[w] = svx * inv_sp; uspy_[w] = svy * inv_sp;
        float rb2 = sqrtf(offx[w] * offx[w] + offy[w] * offy[w]);
        float invb = 1.0f / (rb2 + 1e-12f);
        u3x_[w] = -offx[w] * invb; u3y_[w] = -offy[w] * invb;
        float tp = r_sp * ((float)tabN / 0.06f);
        inr_[w] = tp < (float)tabN;
        int ti = (int)tp;
        if (ti > tabN - 1) ti = tabN - 1;
        if (ti < 0) ti = 0;
        ti_[w] = ti; fr_[w] = tp - (float)ti;
    }

    // ---- initial states ----
    float s3[2], s4[2], s5[2];
    float v3x[2], v3y[2], v3z[2], v4x[2], v4y[2], v4z[2], v5x[2], v5y[2], v5z[2];
    {
        float i35 = W_embed[kl] + W_embed[100 + kl];
        float i4  = W_embed[kl] + W_embed[50 + kl];
#pragma unroll
        for (int w = 0; w < 2; ++w) {
            s3[w] = i35; s5[w] = i35; s4[w] = i4;
            v3x[w] = v3y[w] = v3z[w] = 0.0f;
            v4x[w] = v4y[w] = v4z[w] = 0.0f;
            v5x[w] = v5y[w] = v5z[w] = 0.0f;
        }
    }

    for (int l = 0; l < 6; ++l) {
        __syncthreads();   // overlay region free

        // ---- per-layer T (L2-resident, pair layout) + pre loads ----
        float s1l = pre[l * 50 + kl];
        const float* wbp = pre + 300 + l * 250;
        float wb0 = wbp[kl], wb1 = wbp[50 + kl], wb2 = wbp[100 + kl],
              wb3 = wbp[150 + kl], wb4 = wbp[200 + kl];

        const float THIRD = 1.0f / 3.0f;
#pragma unroll
        for (int w = 0; w < 2; ++w) {
            const float* tb = T + ((size_t)(l * (tabN + 1) + ti_[w])) * 100 + 2 * kl;
            float2 t0 = *(const float2*)tb;
            float2 t1 = *(const float2*)(tb + 100);
            float wsp0 = inr_[w] ? (t0.x + fr_[w] * (t1.x - t0.x)) : 0.0f;
            float wsp1 = inr_[w] ? (t0.y + fr_[w] * (t1.y - t0.y)) : 0.0f;

            float u3x = u3x_[w], u3y = u3y_[w];
            float dot3 = v4x[w] * u3x + v4y[w] * u3y;
            float ms3 = wb0 * s4[w] + wb2 * dot3;
            float ms5 = wb0 * s4[w] - wb2 * dot3;
            float ms4 = wsp0 * s1l;
            float bAx = wb1 * s4[w] * u3x - wb3 * v4z[w] * u3y;
            float bAy = wb1 * s4[w] * u3y + wb3 * v4z[w] * u3x;
            float bBx = wb4 * (dot3 * u3x - v4x[w] * THIRD);
            float bBy = wb4 * (dot3 * u3y - v4y[w] * THIRD);
            float crz = wb3 * (v4x[w] * u3y - v4y[w] * u3x);
            float mzc = -wb4 * v4z[w] * THIRD;

            float vals[12];
            vals[0] = s3[w] + ms3;
            vals[1] = s4[w] + ms4;
            vals[2] = s5[w] + ms5;
            vals[3] = v3x[w] + bAx + bBx;
            vals[4] = v3y[w] + bAy + bBy;
            vals[5] = v3z[w] + crz + mzc;
            vals[6] = v4x[w] + wsp1 * s1l * uspx_[w];
            vals[7] = v4y[w] + wsp1 * s1l * uspy_[w];
            vals[8] = v4z[w];
            vals[9]  = v5x[w] - bAx + bBx;
            vals[10] = v5y[w] - bAy + bBy;
            vals[11] = v5z[w] - crz + mzc;

            int wv = wave * 2 + w;
#pragma unroll
            for (int q = 0; q < 12; ++q) {
                int row = (q < 3) ? (wv * 3 + q) : (24 + wv * 9 + (q - 3));
                float x = (lane < 50) ? vals[q] : 0.0f;
                _Float16 hi = (_Float16)x;
                _Float16 lo = (_Float16)(x - (float)hi);
                int col = lane ^ ((row & 7) << 3);
                A[row * 128 + col]      = hi;
                A[row * 128 + col + 64] = lo;
            }
        }
        __syncthreads();   // A complete (no pad rows needed: garbage C rows unstored)

        // ---- MFMA phase (B loads inside each sub-block: short live ranges) ----
        f4 cst[9];
        const _Float16* B1l = B1 + (size_t)l * B1_PER_L;
        const _Float16* B2l = B2 + (size_t)l * B2_PER_L;

        // ji0: H, n-tile = wave (n = wave*16+fm <= 63)
        {
            const _Float16* bp = B1l + (wave * 16 + fm) * 192 + fq * 8;
            h8 b0 = ldh8(bp), b1 = ldh8(bp + 32), b2 = ldh8(bp + 64),
               b3 = ldh8(bp + 96), b4 = ldh8(bp + 128), b5 = ldh8(bp + 160);
#pragma unroll
            for (int mt = 0; mt < 2; ++mt) {
                h8 a0, a1, a2, a3;
                lda(mt * 16 + fm, a0, a1, a2, a3);
                f4 acc = {0.0f, 0.0f, 0.0f, 0.0f};
                acc = __builtin_amdgcn_mfma_f32_16x16x32_f16(a0, b0, acc, 0, 0, 0);
                acc = __builtin_amdgcn_mfma_f32_16x16x32_f16(a1, b1, acc, 0, 0, 0);
                acc = __builtin_amdgcn_mfma_f32_16x16x32_f16(a2, b2, acc, 0, 0, 0);
                acc = __builtin_amdgcn_mfma_f32_16x16x32_f16(a3, b3, acc, 0, 0, 0);
                acc = __builtin_amdgcn_mfma_f32_16x16x32_f16(a0, b4, acc, 0, 0, 0);
                acc = __builtin_amdgcn_mfma_f32_16x16x32_f16(a1, b5, acc, 0, 0, 0);
                cst[mt] = acc;
            }
        }
        // ji1: H, n-tile = 4+wave (waves 0..2)
        if (wave < 3) {
            const _Float16* bp = B1l + ((4 + wave) * 16 + fm) * 192 + fq * 8;
            h8 b0 = ldh8(bp), b1 = ldh8(bp + 32), b2 = ldh8(bp + 64),
               b3 = ldh8(bp + 96), b4 = ldh8(bp + 128), b5 = ldh8(bp + 160);
#pragma unroll
            for (int mt = 0; mt < 2; ++mt) {
                h8 a0, a1, a2, a3;
                lda(mt * 16 + fm, a0, a1, a2, a3);
                f4 acc = {0.0f, 0.0f, 0.0f, 0.0f};
                acc = __builtin_amdgcn_mfma_f32_16x16x32_f16(a0, b0, acc, 0, 0, 0);
                acc = __builtin_amdgcn_mfma_f32_16x16x32_f16(a1, b1, acc, 0, 0, 0);
                acc = __builtin_amdgcn_mfma_f32_16x16x32_f16(a2, b2, acc, 0, 0, 0);
                acc = __builtin_amdgcn_mfma_f32_16x16x32_f16(a3, b3, acc, 0, 0, 0);
                acc = __builtin_amdgcn_mfma_f32_16x16x32_f16(a0, b4, acc, 0, 0, 0);
                acc = __builtin_amdgcn_mfma_f32_16x16x32_f16(a1, b5, acc, 0, 0, 0);
                cst[2 + mt] = acc;
            }
        }
        // ji2: Q, n-tile = wave; Q A-rows start at 24
        {
            const _Float16* bp = B2l + (wave * 16 + fm) * 192 + fq * 8;
            h8 b0 = ldh8(bp), b1 = ldh8(bp + 32), b2 = ldh8(bp + 64),
               b3 = ldh8(bp + 96), b4 = ldh8(bp + 128), b5 = ldh8(bp + 160);
#pragma unroll
            for (int mt = 0; mt < 5; ++mt) {
                h8 a0, a1, a2, a3;
                lda(24 + mt * 16 + fm, a0, a1, a2, a3);
                f4 acc = {0.0f, 0.0f, 0.0f, 0.0f};
                acc = __builtin_amdgcn_mfma_f32_16x16x32_f16(a0, b0, acc, 0, 0, 0);
                acc = __builtin_amdgcn_mfma_f32_16x16x32_f16(a1, b1, acc, 0, 0, 0);
                acc = __builtin_amdgcn_mfma_f32_16x16x32_f16(a2, b2, acc, 0, 0, 0);
                acc = __builtin_amdgcn_mfma_f32_16x16x32_f16(a3, b3, acc, 0, 0, 0);
                acc = __builtin_amdgcn_mfma_f32_16x16x32_f16(a0, b4, acc, 0, 0, 0);
                acc = __builtin_amdgcn_mfma_f32_16x16x32_f16(a1, b5, acc, 0, 0, 0);
                cst[4 + mt] = acc;
            }
        }
        __syncthreads();   // all A-reads done -> overlay safe

        // ---- C writes, transposed; skip discarded rows (>=24 H, >=72 Q) ----
        {
            int n0 = wave * 16 + fm;                     // < 64
#pragma unroll
            for (int mt = 0; mt < 2; ++mt)
#pragma unroll
                for (int i = 0; i < 4; ++i) {
                    int r = mt * 16 + fq * 4 + i;
                    if (r < 24) outHT[r * 100 + n0] = cst[mt][i];
                }
            if (wave < 3) {
                int n1 = (4 + wave) * 16 + fm;           // 64..111
                if (n1 < 100) {
#pragma unroll
                    for (int mt = 0; mt < 2; ++mt)
#pragma unroll
                        for (int i = 0; i < 4; ++i) {
                            int r = mt * 16 + fq * 4 + i;
                            if (r < 24) outHT[r * 100 + n1] = cst[2 + mt][i];
                        }
                }
            }
            if (n0 < 50) {
#pragma unroll
                for (int mt = 0; mt < 5; ++mt)
#pragma unroll
                    for (int i = 0; i < 4; ++i) {
                        int r = mt * 16 + fq * 4 + i;
                        if (r < 72) outQT[r * 50 + n0] = cst[4 + mt][i];
                    }
            }
        }
        __syncthreads();   // outputs ready

        // ---- readback + activations (stride-1 in kl: conflict-free) ----
#pragma unroll
        for (int w = 0; w < 2; ++w) {
            int wv = wave * 2 + w;
            int mb = wv * 3, qb = wv * 9;
            float as3 = outHT[(mb    ) * 100 + kl];
            float as4 = outHT[(mb + 1) * 100 + kl];
            float as5 = outHT[(mb + 2) * 100 + kl];
            float ag3 = outHT[(mb    ) * 100 + 50 + kl];
            float ag4 = outHT[(mb + 1) * 100 + 50 + kl];
            float ag5 = outHT[(mb + 2) * 100 + 50 + kl];
            float g3 = sigm_(ag3), g4 = sigm_(ag4), g5 = sigm_(ag5);
            s3[w] = silu_(as3); s4[w] = silu_(as4); s5[w] = silu_(as5);
            v3x[w] = outQT[(qb    ) * 50 + kl] * g3;
            v3y[w] = outQT[(qb + 1) * 50 + kl] * g3;
            v3z[w] = outQT[(qb + 2) * 50 + kl] * g3;
            v4x[w] = outQT[(qb + 3) * 50 + kl] * g4;
            v4y[w] = outQT[(qb + 4) * 50 + kl] * g4;
            v4z[w] = outQT[(qb + 5) * 50 + kl] * g4;
            v5x[w] = outQT[(qb + 6) * 50 + kl] * g5;
            v5y[w] = outQT[(qb + 7) * 50 + kl] * g5;
            v5z[w] = outQT[(qb + 8) * 50 + kl] * g5;
        }
    }

    // ---- output epilogue ----
    float wo = (lane < 50) ? W_out[lane] : 0.0f;
#pragma unroll
    for (int w = 0; w < 2; ++w) {
        float px  = (v3x[w] + v4x[w] + v5x[w]) * wo;
        float py  = (v3y[w] + v4y[w] + v5y[w]) * wo;
        float dxv = (v3x[w] - v5x[w]) * wo;
        float dyv = (v3y[w] - v5y[w]) * wo;
#pragma unroll
        for (int o = 32; o > 0; o >>= 1) {
            px  += __shfl_xor(px, o);
            py  += __shfl_xor(py, o);
            dxv += __shfl_xor(dxv, o);
            dyv += __shfl_xor(dyv, o);
        }
        if (lane == 0) {
            int wid = blockIdx.x * 8 + wave * 2 + w;
            int b = wid >> 9, tw = wid & 511;
            float* op = out + ((size_t)(b * 514 + (tw + 1))) * 3;
            op[0] = px;
            op[1] = py;
            op[2] = offx[w] * dyv - offy[w] * dxv;
        }
    }
}

// ---------------------------------------------------------------------------
extern "C" void kernel_launch(void* const* d_in, const int* in_sizes, int n_in,
                              void* d_out, int out_size, void* d_ws, size_t ws_size,
                              hipStream_t stream) {
    const float* y       = (const float*)d_in[0];
    const float* W_embed = (const float*)d_in[1];
    const float* Wr1     = (const float*)d_in[2];
    const float* br1     = (const float*)d_in[3];
    const float* Wr2     = (const float*)d_in[4];
    const float* Ws      = (const float*)d_in[5];
    const float* Wv      = (const float*)d_in[6];
    const float* Wg      = (const float*)d_in[7];
    const float* W_out   = (const float*)d_in[8];
    float* out = (float*)d_out;

    _Float16* Bws = (_Float16*)d_ws;                         // 405504 B
    float* pre = (float*)((char*)d_ws + B_TOT * 2);          // 1800 floats
    float* T   = pre + 1800;

    // tabN=1024: table = 2.46 MB -> per-XCD-L2-resident; absmax verified
    // unchanged vs tabN=2048 (precision is fp16-split-dominated).
    int tabN = 1024;
    while (tabN > 64 &&
           (size_t)B_TOT * 2 + (size_t)(1800 + 6 * (tabN + 1) * 100) * sizeof(float) > ws_size)
        tabN >>= 1;

    int nTb = (6 * (tabN + 1) + 3) / 4;
    int nFb = (B_TOT + 255) / 256;
    precompute_all<<<1 + nTb + nFb, 256, 0, stream>>>(
        W_embed, Wr1, br1, Wr2, Ws, Wg, Wv, pre, T, tabN, Bws, out, nTb);
    fused_main<<<4096, 256, 0, stream>>>(y, W_embed, W_out, pre, T, tabN, Bws, out);
}

// Round 5
// 301.840 us; speedup vs baseline: 1.9449x; 1.2478x over previous
//
#include <hip/hip_runtime.h>
#include <math.h>

#define PI_F 3.14159265358979323846f

typedef _Float16 h8 __attribute__((ext_vector_type(8)));
typedef float f4 __attribute__((ext_vector_type(4)));

__device__ __forceinline__ float sigm_(float x){ return 1.0f/(1.0f+__expf(-x)); }
__device__ __forceinline__ float silu_(float x){ return x*sigm_(x); }
__device__ __forceinline__ h8 ldh8(const _Float16* p){
    return __builtin_bit_cast(h8, *(const float4*)(p));
}

// B layout (fp16, in d_ws):
//   B1T: per layer [n<112][k<192]  (n<50: Ws col, 50..99: Wg col, 100+: 0)
//   B2T: per layer [n<64][k<192]   (n<50: Wv col, else 0)
//   k segments: [0,50): W_hi(c=k) | [64,114): W_hi(c=k-64) | [128,178): W_lo(c=k-128)
#define B1_PER_L 21504
#define B2_PER_L 12288
#define B1_TOT   129024
#define B_TOT    202752

// A row stride in halves: 136 (=68 words, 68 mod 32 = 4 -> 8-lane batches of
// b128 frag reads hit distinct 4-bank groups; same conflict structure as the
// r0-proven 152, but LDS = 112*136*2 = 30464 B -> 5 blocks/CU when scratch==0.
// SPILL RULE (r0-r4 evidence): any scratch use caps occupancy at ~4 blocks AND
// adds GB-scale traffic. Keep per-thread pressure at the r0 64-VGPR envelope:
// no prefetch registers, no swizzle address temps, launch_bounds (256,4).
#define ASTR 136

// ---------------------------------------------------------------------------
// K1 (merged): block 0 = pre[] + output boundary zeros; blocks [1..nTb] =
// spine table (4 entries/block, 1/wave); blocks (nTb..] = fill_B.
// T layout: per entry e, 50 float2 pairs {col kl, col 50+kl}.
// ---------------------------------------------------------------------------
__global__ void precompute_all(const float* __restrict__ W_embed,
                               const float* __restrict__ Wr1,
                               const float* __restrict__ br1,
                               const float* __restrict__ Wr2,
                               const float* __restrict__ Ws,
                               const float* __restrict__ Wg,
                               const float* __restrict__ Wv,
                               float* __restrict__ pre,
                               float* __restrict__ T,
                               int tabN,
                               _Float16* __restrict__ B,
                               float* __restrict__ out,
                               int nTb)
{
    const int bid = blockIdx.x;
    const int tid = threadIdx.x;
    const float wdt = 0.06f / 9.0f;

    if (bid == 0) {
        // ---- zero output boundary rows (t=0, t=513) : 64 batches x 6 floats
        for (int i = tid; i < 384; i += 256) {
            int b = i / 6, r = i - b * 6;
            int t = (r < 3) ? 0 : 513;
            out[((size_t)(b * 514 + t)) * 3 + (r % 3)] = 0.0f;
        }
        // ---- pre[]: s1 trajectory + bar-edge weights
        __shared__ float s1[50];
        __shared__ float hid[64];
        if (tid < 50) s1[tid] = W_embed[tid] + W_embed[50 + tid];
        __syncthreads();

        const float rbar = 0.05f;
        const float fcb = 0.5f * (__cosf(PI_F * (rbar / 0.06f)) + 1.0f);
        float emb[12];
#pragma unroll
        for (int i = 0; i < 10; ++i) {
            float d = (rbar - (float)i * wdt) / wdt;
            emb[i] = __expf(-d * d) * fcb;
        }
        emb[10] = 0.0f; emb[11] = 1.0f;

        for (int l = 0; l < 6; ++l) {
            if (tid < 50) pre[l * 50 + tid] = s1[tid];
            if (tid < 64) {
                float a = br1[l * 64 + tid];
#pragma unroll
                for (int i = 0; i < 12; ++i) a += emb[i] * Wr1[l * 768 + i * 64 + tid];
                hid[tid] = silu_(a);
            }
            __syncthreads();
            for (int m = tid; m < 250; m += 256) {
                float acc = 0.0f;
                for (int j = 0; j < 64; ++j) acc += hid[j] * Wr2[l * 16000 + j * 250 + m];
                pre[300 + l * 250 + m] = acc * fcb;
            }
            float sacc = 0.0f;
            if (tid < 50) {
                for (int c = 0; c < 50; ++c) sacc += s1[c] * Ws[l * 2500 + c * 50 + tid];
            }
            __syncthreads();
            if (tid < 50) s1[tid] = silu_(sacc);
            __syncthreads();
        }
    } else if (bid <= nTb) {
        // ---- spine-edge table entry per wave ----
        const int e = (bid - 1) * 4 + (tid >> 6);
        const int lane = tid & 63;
        const int total = 6 * (tabN + 1);
        if (e >= total) return;
        const int l = e / (tabN + 1);
        const int i = e - l * (tabN + 1);

        float r = (float)i * (0.06f / (float)tabN);
        float t = fminf(r * (1.0f / 0.06f), 1.0f);
        float fc = 0.5f * (__cosf(PI_F * t) + 1.0f);
        float emb[10];
#pragma unroll
        for (int k = 0; k < 10; ++k) {
            float d = (r - (float)k * wdt) / wdt;
            emb[k] = __expf(-d * d) * fc;
        }
        float a = br1[l * 64 + lane] + Wr1[l * 768 + 640 + lane];  // edge_attr [1,0]
#pragma unroll
        for (int k = 0; k < 10; ++k) a += emb[k] * Wr1[l * 768 + k * 64 + lane];
        float hv = silu_(a);

        float acc0 = 0.0f, acc1 = 0.0f;
        const float* wr2 = Wr2 + l * 16000;
        for (int j = 0; j < 64; ++j) {
            float hj = __shfl(hv, j);
            acc0 += hj * wr2[j * 250 + lane];
            acc1 += hj * wr2[j * 250 + 64 + lane];
        }
        // pair layout: T[e][2*c]   = col c      (acc0 @ lane c)
        //              T[e][2*c+1] = col 50+c   (c<14: acc0 @ lane 50+c, else acc1 @ lane c-14)
        float* tp = T + (size_t)e * 100;
        float sh0 = __shfl(acc0, lane + 50);   // wraps mod 64; selected only for lane<14
        float sh1 = __shfl(acc1, lane - 14);
        float vb = ((lane < 14) ? sh0 : sh1) * fc;
        if (lane < 50) *(float2*)(tp + 2 * lane) = make_float2(acc0 * fc, vb);
    } else {
        // ---- fill_B ----
        int idx = (bid - 1 - nTb) * 256 + tid;
        if (idx >= B_TOT) return;
        int l, n, k, which;
        size_t off;
        if (idx < B1_TOT) {
            l = idx / B1_PER_L; int r = idx - l * B1_PER_L;
            n = r / 192; k = r - n * 192; which = 0;
            off = (size_t)l * B1_PER_L + n * 192 + k;
        } else {
            int j = idx - B1_TOT;
            l = j / B2_PER_L; int r = j - l * B2_PER_L;
            n = r / 192; k = r - n * 192; which = 1;
            off = B1_TOT + (size_t)l * B2_PER_L + n * 192 + k;
        }
        int seg = -1, c = 0;
        if (k < 50)                  { seg = 0; c = k; }
        else if (k >= 64 && k < 114) { seg = 1; c = k - 64; }
        else if (k >= 128 && k < 178){ seg = 2; c = k - 128; }
        _Float16 val = (_Float16)0.0f;
        if (seg >= 0) {
            float w = 0.0f;
            if (which == 0) {
                if (n < 50)       w = Ws[l * 2500 + c * 50 + n];
                else if (n < 100) w = Wg[l * 2500 + c * 50 + (n - 50)];
            } else {
                if (n < 50)       w = Wv[l * 2500 + c * 50 + n];
            }
            _Float16 hi = (_Float16)w;
            val = (seg < 2) ? hi : (_Float16)(w - (float)hi);
        }
        B[off] = val;
    }
}

// ---------------------------------------------------------------------------
// K2: fused forward. Block = 8 windows (2/wave). A rows stride 136 halves.
// C stored TRANSPOSED (outHT[32][100], outQT[80][50]) in overlay. Structure
// is the r0-proven zero-spill form: inline T/pre loads at loop top (pair-T,
// L2-resident at tabN=1024), B loads inside each MFMA sub-block.
// ---------------------------------------------------------------------------
__global__ __launch_bounds__(256, 4)
void fused_main(const float* __restrict__ y,
                const float* __restrict__ W_embed,
                const float* __restrict__ W_out,
                const float* __restrict__ pre,
                const float* __restrict__ T,
                int tabN,
                const _Float16* __restrict__ Bws,
                float* __restrict__ out)
{
    __shared__ __align__(16) char LB[112 * ASTR * 2];   // 30464 B
    _Float16* A   = (_Float16*)LB;
    float* outHT  = (float*)LB;          // [32][100]
    float* outQT  = (float*)LB + 3200;   // [80][50]

    const int tid  = threadIdx.x;
    const int wave = tid >> 6;
    const int lane = tid & 63;
    const int kl   = (lane < 50) ? lane : 49;
    const int fm   = lane & 15;
    const int fq   = lane >> 4;

    const _Float16* B1 = Bws;
    const _Float16* B2 = Bws + B1_TOT;

    // ---- per-window geometry ----
    float offx[2], offy[2], u3x_[2], u3y_[2], uspx_[2], uspy_[2], fr_[2];
    int   ti_[2], inr_[2];
#pragma unroll
    for (int w = 0; w < 2; ++w) {
        int wid = blockIdx.x * 8 + wave * 2 + w;
        int b = wid >> 9, tw = wid & 511;
        const float* yb = y + ((size_t)(b * 514 + tw)) * 6;
        float c0x = yb[0], c0y = yb[1];
        float c1x = yb[6], c1y = yb[7], a1 = yb[8];
        float sn, cs; __sincosf(a1, &sn, &cs);
        offx[w] = -0.05f * sn; offy[w] = 0.05f * cs;
        float svx = c0x - c1x, svy = c0y - c1y;
        float r_sp = sqrtf(svx * svx + svy * svy);
        float inv_sp = 1.0f / (r_sp + 1e-12f);
        uspx_[w] = svx * inv_sp; uspy_[w] = svy * inv_sp;
        float rb2 = sqrtf(offx[w] * offx[w] + offy[w] * offy[w]);
        float invb = 1.0f / (rb2 + 1e-12f);
        u3x_[w] = -offx[w] * invb; u3y_[w] = -offy[w] * invb;
        float tp = r_sp * ((float)tabN / 0.06f);
        inr_[w] = tp < (float)tabN;
        int ti = (int)tp;
        if (ti > tabN - 1) ti = tabN - 1;
        if (ti < 0) ti = 0;
        ti_[w] = ti; fr_[w] = tp - (float)ti;
    }

    // ---- initial states ----
    float s3[2], s4[2], s5[2];
    float v3x[2], v3y[2], v3z[2], v4x[2], v4y[2], v4z[2], v5x[2], v5y[2], v5z[2];
    {
        float i35 = W_embed[kl] + W_embed[100 + kl];
        float i4  = W_embed[kl] + W_embed[50 + kl];
#pragma unroll
        for (int w = 0; w < 2; ++w) {
            s3[w] = i35; s5[w] = i35; s4[w] = i4;
            v3x[w] = v3y[w] = v3z[w] = 0.0f;
            v4x[w] = v4y[w] = v4z[w] = 0.0f;
            v5x[w] = v5y[w] = v5z[w] = 0.0f;
        }
    }

    for (int l = 0; l < 6; ++l) {
        __syncthreads();   // overlay region free

        // ---- per-layer T (L2-resident, pair layout) + pre loads ----
        float s1l = pre[l * 50 + kl];
        const float* wbp = pre + 300 + l * 250;
        float wb0 = wbp[kl], wb1 = wbp[50 + kl], wb2 = wbp[100 + kl],
              wb3 = wbp[150 + kl], wb4 = wbp[200 + kl];

        const float THIRD = 1.0f / 3.0f;
#pragma unroll
        for (int w = 0; w < 2; ++w) {
            const float* tb = T + ((size_t)(l * (tabN + 1) + ti_[w])) * 100 + 2 * kl;
            float2 t0 = *(const float2*)tb;
            float2 t1 = *(const float2*)(tb + 100);
            float wsp0 = inr_[w] ? (t0.x + fr_[w] * (t1.x - t0.x)) : 0.0f;
            float wsp1 = inr_[w] ? (t0.y + fr_[w] * (t1.y - t0.y)) : 0.0f;

            float u3x = u3x_[w], u3y = u3y_[w];
            float dot3 = v4x[w] * u3x + v4y[w] * u3y;
            float ms3 = wb0 * s4[w] + wb2 * dot3;
            float ms5 = wb0 * s4[w] - wb2 * dot3;
            float ms4 = wsp0 * s1l;
            float bAx = wb1 * s4[w] * u3x - wb3 * v4z[w] * u3y;
            float bAy = wb1 * s4[w] * u3y + wb3 * v4z[w] * u3x;
            float bBx = wb4 * (dot3 * u3x - v4x[w] * THIRD);
            float bBy = wb4 * (dot3 * u3y - v4y[w] * THIRD);
            float crz = wb3 * (v4x[w] * u3y - v4y[w] * u3x);
            float mzc = -wb4 * v4z[w] * THIRD;

            float vals[12];
            vals[0] = s3[w] + ms3;
            vals[1] = s4[w] + ms4;
            vals[2] = s5[w] + ms5;
            vals[3] = v3x[w] + bAx + bBx;
            vals[4] = v3y[w] + bAy + bBy;
            vals[5] = v3z[w] + crz + mzc;
            vals[6] = v4x[w] + wsp1 * s1l * uspx_[w];
            vals[7] = v4y[w] + wsp1 * s1l * uspy_[w];
            vals[8] = v4z[w];
            vals[9]  = v5x[w] - bAx + bBx;
            vals[10] = v5y[w] - bAy + bBy;
            vals[11] = v5z[w] - crz + mzc;

            int wv = wave * 2 + w;
#pragma unroll
            for (int q = 0; q < 12; ++q) {
                int row = (q < 3) ? (wv * 3 + q) : (32 + wv * 9 + (q - 3));
                float x = (lane < 50) ? vals[q] : 0.0f;
                _Float16 hi = (_Float16)x;
                _Float16 lo = (_Float16)(x - (float)hi);
                A[row * ASTR + lane]      = hi;
                A[row * ASTR + 64 + lane] = lo;
            }
        }
        // zero pad rows (H 24..31, Q-block rows 104..111)
        {
            int pr  = tid >> 4;
            int row = (pr < 8) ? (24 + pr) : (96 + pr);
            f4 z = {0.0f, 0.0f, 0.0f, 0.0f};
            *(f4*)(A + row * ASTR + (tid & 15) * 8) = z;
        }
        __syncthreads();   // A complete

        // ---- MFMA phase (B loads inside each sub-block: short live ranges) ----
        f4 cst[9];
        const _Float16* B1l = B1 + (size_t)l * B1_PER_L;
        const _Float16* B2l = B2 + (size_t)l * B2_PER_L;

        // ji0: H, n-tile = wave (n = wave*16+fm <= 63)
        {
            const _Float16* bp = B1l + (wave * 16 + fm) * 192 + fq * 8;
            h8 b0 = ldh8(bp), b1 = ldh8(bp + 32), b2 = ldh8(bp + 64),
               b3 = ldh8(bp + 96), b4 = ldh8(bp + 128), b5 = ldh8(bp + 160);
#pragma unroll
            for (int mt = 0; mt < 2; ++mt) {
                const _Float16* ap = A + (mt * 16 + fm) * ASTR + fq * 8;
                h8 a0 = ldh8(ap), a1 = ldh8(ap + 32), a2 = ldh8(ap + 64), a3 = ldh8(ap + 96);
                f4 acc = {0.0f, 0.0f, 0.0f, 0.0f};
                acc = __builtin_amdgcn_mfma_f32_16x16x32_f16(a0, b0, acc, 0, 0, 0);
                acc = __builtin_amdgcn_mfma_f32_16x16x32_f16(a1, b1, acc, 0, 0, 0);
                acc = __builtin_amdgcn_mfma_f32_16x16x32_f16(a2, b2, acc, 0, 0, 0);
                acc = __builtin_amdgcn_mfma_f32_16x16x32_f16(a3, b3, acc, 0, 0, 0);
                acc = __builtin_amdgcn_mfma_f32_16x16x32_f16(a0, b4, acc, 0, 0, 0);
                acc = __builtin_amdgcn_mfma_f32_16x16x32_f16(a1, b5, acc, 0, 0, 0);
                cst[mt] = acc;
            }
        }
        // ji1: H, n-tile = 4+wave (waves 0..2)
        if (wave < 3) {
            const _Float16* bp = B1l + ((4 + wave) * 16 + fm) * 192 + fq * 8;
            h8 b0 = ldh8(bp), b1 = ldh8(bp + 32), b2 = ldh8(bp + 64),
               b3 = ldh8(bp + 96), b4 = ldh8(bp + 128), b5 = ldh8(bp + 160);
#pragma unroll
            for (int mt = 0; mt < 2; ++mt) {
                const _Float16* ap = A + (mt * 16 + fm) * ASTR + fq * 8;
                h8 a0 = ldh8(ap), a1 = ldh8(ap + 32), a2 = ldh8(ap + 64), a3 = ldh8(ap + 96);
                f4 acc = {0.0f, 0.0f, 0.0f, 0.0f};
                acc = __builtin_amdgcn_mfma_f32_16x16x32_f16(a0, b0, acc, 0, 0, 0);
                acc = __builtin_amdgcn_mfma_f32_16x16x32_f16(a1, b1, acc, 0, 0, 0);
                acc = __builtin_amdgcn_mfma_f32_16x16x32_f16(a2, b2, acc, 0, 0, 0);
                acc = __builtin_amdgcn_mfma_f32_16x16x32_f16(a3, b3, acc, 0, 0, 0);
                acc = __builtin_amdgcn_mfma_f32_16x16x32_f16(a0, b4, acc, 0, 0, 0);
                acc = __builtin_amdgcn_mfma_f32_16x16x32_f16(a1, b5, acc, 0, 0, 0);
                cst[2 + mt] = acc;
            }
        }
        // ji2: Q, n-tile = wave
        {
            const _Float16* bp = B2l + (wave * 16 + fm) * 192 + fq * 8;
            h8 b0 = ldh8(bp), b1 = ldh8(bp + 32), b2 = ldh8(bp + 64),
               b3 = ldh8(bp + 96), b4 = ldh8(bp + 128), b5 = ldh8(bp + 160);
#pragma unroll
            for (int mt = 0; mt < 5; ++mt) {
                const _Float16* ap = A + (32 + mt * 16 + fm) * ASTR + fq * 8;
                h8 a0 = ldh8(ap), a1 = ldh8(ap + 32), a2 = ldh8(ap + 64), a3 = ldh8(ap + 96);
                f4 acc = {0.0f, 0.0f, 0.0f, 0.0f};
                acc = __builtin_amdgcn_mfma_f32_16x16x32_f16(a0, b0, acc, 0, 0, 0);
                acc = __builtin_amdgcn_mfma_f32_16x16x32_f16(a1, b1, acc, 0, 0, 0);
                acc = __builtin_amdgcn_mfma_f32_16x16x32_f16(a2, b2, acc, 0, 0, 0);
                acc = __builtin_amdgcn_mfma_f32_16x16x32_f16(a3, b3, acc, 0, 0, 0);
                acc = __builtin_amdgcn_mfma_f32_16x16x32_f16(a0, b4, acc, 0, 0, 0);
                acc = __builtin_amdgcn_mfma_f32_16x16x32_f16(a1, b5, acc, 0, 0, 0);
                cst[4 + mt] = acc;
            }
        }
        __syncthreads();   // all A-reads done -> overlay safe

        // ---- C writes, transposed (lanes stride-1 in n: conflict-free) ----
        {
            int n0 = wave * 16 + fm;                     // < 64
#pragma unroll
            for (int mt = 0; mt < 2; ++mt)
#pragma unroll
                for (int i = 0; i < 4; ++i)
                    outHT[(mt * 16 + fq * 4 + i) * 100 + n0] = cst[mt][i];
            if (wave < 3) {
                int n1 = (4 + wave) * 16 + fm;           // 64..111
                if (n1 < 100) {
#pragma unroll
                    for (int mt = 0; mt < 2; ++mt)
#pragma unroll
                        for (int i = 0; i < 4; ++i)
                            outHT[(mt * 16 + fq * 4 + i) * 100 + n1] = cst[2 + mt][i];
                }
            }
            if (n0 < 50) {
#pragma unroll
                for (int mt = 0; mt < 5; ++mt)
#pragma unroll
                    for (int i = 0; i < 4; ++i)
                        outQT[(mt * 16 + fq * 4 + i) * 50 + n0] = cst[4 + mt][i];
            }
        }
        __syncthreads();   // outputs ready

        // ---- readback + activations (stride-1 in kl: conflict-free) ----
#pragma unroll
        for (int w = 0; w < 2; ++w) {
            int wv = wave * 2 + w;
            int mb = wv * 3, qb = wv * 9;
            float as3 = outHT[(mb    ) * 100 + kl];
            float as4 = outHT[(mb + 1) * 100 + kl];
            float as5 = outHT[(mb + 2) * 100 + kl];
            float ag3 = outHT[(mb    ) * 100 + 50 + kl];
            float ag4 = outHT[(mb + 1) * 100 + 50 + kl];
            float ag5 = outHT[(mb + 2) * 100 + 50 + kl];
            float g3 = sigm_(ag3), g4 = sigm_(ag4), g5 = sigm_(ag5);
            s3[w] = silu_(as3); s4[w] = silu_(as4); s5[w] = silu_(as5);
            v3x[w] = outQT[(qb    ) * 50 + kl] * g3;
            v3y[w] = outQT[(qb + 1) * 50 + kl] * g3;
            v3z[w] = outQT[(qb + 2) * 50 + kl] * g3;
            v4x[w] = outQT[(qb + 3) * 50 + kl] * g4;
            v4y[w] = outQT[(qb + 4) * 50 + kl] * g4;
            v4z[w] = outQT[(qb + 5) * 50 + kl] * g4;
            v5x[w] = outQT[(qb + 6) * 50 + kl] * g5;
            v5y[w] = outQT[(qb + 7) * 50 + kl] * g5;
            v5z[w] = outQT[(qb + 8) * 50 + kl] * g5;
        }
    }

    // ---- output epilogue ----
    float wo = (lane < 50) ? W_out[lane] : 0.0f;
#pragma unroll
    for (int w = 0; w < 2; ++w) {
        float px  = (v3x[w] + v4x[w] + v5x[w]) * wo;
        float py  = (v3y[w] + v4y[w] + v5y[w]) * wo;
        float dxv = (v3x[w] - v5x[w]) * wo;
        float dyv = (v3y[w] - v5y[w]) * wo;
#pragma unroll
        for (int o = 32; o > 0; o >>= 1) {
            px  += __shfl_xor(px, o);
            py  += __shfl_xor(py, o);
            dxv += __shfl_xor(dxv, o);
            dyv += __shfl_xor(dyv, o);
        }
        if (lane == 0) {
            int wid = blockIdx.x * 8 + wave * 2 + w;
            int b = wid >> 9, tw = wid & 511;
            float* op = out + ((size_t)(b * 514 + (tw + 1))) * 3;
            op[0] = px;
            op[1] = py;
            op[2] = offx[w] * dyv - offy[w] * dxv;
        }
    }
}

// ---------------------------------------------------------------------------
extern "C" void kernel_launch(void* const* d_in, const int* in_sizes, int n_in,
                              void* d_out, int out_size, void* d_ws, size_t ws_size,
                              hipStream_t stream) {
    const float* y       = (const float*)d_in[0];
    const float* W_embed = (const float*)d_in[1];
    const float* Wr1     = (const float*)d_in[2];
    const float* br1     = (const float*)d_in[3];
    const float* Wr2     = (const float*)d_in[4];
    const float* Ws      = (const float*)d_in[5];
    const float* Wv      = (const float*)d_in[6];
    const float* Wg      = (const float*)d_in[7];
    const float* W_out   = (const float*)d_in[8];
    float* out = (float*)d_out;

    _Float16* Bws = (_Float16*)d_ws;                         // 405504 B
    float* pre = (float*)((char*)d_ws + B_TOT * 2);          // 1800 floats
    float* T   = pre + 1800;

    // tabN=1024: table = 2.46 MB -> per-XCD-L2-resident; absmax verified
    // unchanged vs tabN=2048 across r2-r4 (precision is fp16-split-dominated).
    int tabN = 1024;
    while (tabN > 64 &&
           (size_t)B_TOT * 2 + (size_t)(1800 + 6 * (tabN + 1) * 100) * sizeof(float) > ws_size)
        tabN >>= 1;

    int nTb = (6 * (tabN + 1) + 3) / 4;
    int nFb = (B_TOT + 255) / 256;
    precompute_all<<<1 + nTb + nFb, 256, 0, stream>>>(
        W_embed, Wr1, br1, Wr2, Ws, Wg, Wv, pre, T, tabN, Bws, out, nTb);
    fused_main<<<4096, 256, 0, stream>>>(y, W_embed, W_out, pre, T, tabN, Bws, out);
}